// Round 13
// baseline (231.065 us; speedup 1.0000x reference)
//
#include <hip/hip_runtime.h>
#include <hip/hip_bf16.h>
#include <cstddef>
#include <cstdint>

#define NB 16
#define LIN 512
#define DM 384
#define DC 1536
#define MELMAX 4096
#define LN_EPS 1e-5f

typedef __bf16 bf16x8 __attribute__((ext_vector_type(8)));
typedef float f32x4 __attribute__((ext_vector_type(4)));

#define GL2LDS(gp, lp)                                                                \
    __builtin_amdgcn_global_load_lds((const __attribute__((address_space(1))) void*)(gp), \
                                     (__attribute__((address_space(3))) void*)(lp), 16, 0, 0)

__device__ __forceinline__ float wred(float v) {
#pragma unroll
    for (int m = 32; m >= 1; m >>= 1) v += __shfl_xor(v, m, 64);
    return v;
}

__device__ __forceinline__ unsigned short f2bf(float f) {
    __hip_bfloat16 h = __float2bfloat16(f);
    return *reinterpret_cast<unsigned short*>(&h);
}

__device__ __forceinline__ float bf2f(unsigned short u) {
    return __uint_as_float(((unsigned)u) << 16);
}

// ---------------------------------------------------------------- cumsum (per batch, Hillis-Steele)

__global__ void cumsum_kernel(const int* __restrict__ tgt, int* __restrict__ cum) {
    __shared__ int s[LIN];
    const int b = blockIdx.x, tid = threadIdx.x;
    s[tid] = tgt[b * LIN + tid];
    __syncthreads();
    for (int off = 1; off < LIN; off <<= 1) {
        int v = (tid >= off) ? s[tid - off] : 0;
        __syncthreads();
        s[tid] += v;
        __syncthreads();
    }
    cum[b * LIN + tid] = s[tid];
}

// ---------------------------------------------------------------- length-regulate gather (standalone)

__global__ __launch_bounds__(256) void gather_kernel(const float* __restrict__ x,
                                                     const int* __restrict__ cum,
                                                     float* __restrict__ out) {
    const int wid = (blockIdx.x * 256 + threadIdx.x) >> 6;
    const int lane = threadIdx.x & 63;
    const int b = wid >> 12;
    const int t = wid & (MELMAX - 1);
    const int* c = cum + b * LIN;
    const int total = c[LIN - 1];
    float4* orow = reinterpret_cast<float4*>(out + ((size_t)b * MELMAX + t) * DM);
    if (t < total) {
        int lo = 0, hi = LIN;
        while (lo < hi) { int mid = (lo + hi) >> 1; if (c[mid] > t) hi = mid; else lo = mid + 1; }
        const int idx = lo < (LIN - 1) ? lo : (LIN - 1);
        const float4* xrow = reinterpret_cast<const float4*>(x + ((size_t)b * LIN + idx) * DM);
#pragma unroll
        for (int j = 0; j < 2; ++j) {
            const int p = lane + 64 * j;
            if (p < DM / 4) orow[p] = xrow[p];
        }
    } else {
        const float4 z = make_float4(0.f, 0.f, 0.f, 0.f);
#pragma unroll
        for (int j = 0; j < 2; ++j) {
            const int p = lane + 64 * j;
            if (p < DM / 4) orow[p] = z;
        }
    }
}

// ---------------------------------------------------------------- fused prep: zpad + cast_x + wcast (one launch)

#define ZPAD_BLKS 96
#define CASTX_BLKS 3072   // NB*LIN*DM/4/256
#define WCAST_BLKS 288    // DC*DM/8/256 per matrix

__global__ void prep_kernel(const float* __restrict__ x, unsigned short* __restrict__ xb,
                            unsigned short* __restrict__ hbig, unsigned short* __restrict__ h2b,
                            const float* __restrict__ w1, const float* __restrict__ w2,
                            const float* __restrict__ w3, const float* __restrict__ w4,
                            unsigned short* __restrict__ o1, unsigned short* __restrict__ o2,
                            unsigned short* __restrict__ o3, unsigned short* __restrict__ o4) {
    const int bid = blockIdx.x, tid = threadIdx.x;
    if (bid < ZPAD_BLKS) {
        const int buf = bid >> 5, rem = bid & 31;
        const int b = rem >> 1, row = (rem & 1) ? (LIN + 1) : 0;
        unsigned short* p = buf == 0 ? xb : (buf == 1 ? hbig : h2b);
        const int rl = buf == 1 ? DC : DM;
        unsigned short* base = p + ((size_t)b * (LIN + 2) + row) * rl;
        for (int c = tid; c < rl; c += 256) base[c] = 0;
        return;
    }
    if (bid < ZPAD_BLKS + CASTX_BLKS) {
        const int idx = (bid - ZPAD_BLKS) * 256 + tid;
        const float4 v = reinterpret_cast<const float4*>(x)[idx];
        const int e = idx * 4;
        const int b = e / (LIN * DM);
        const int rem = e - b * (LIN * DM);
        const int l = rem / DM;
        const int c = rem - l * DM;
        ushort4 o;
        o.x = f2bf(v.x); o.y = f2bf(v.y); o.z = f2bf(v.z); o.w = f2bf(v.w);
        *reinterpret_cast<ushort4*>(xb + ((size_t)b * (LIN + 2) + l + 1) * DM + c) = o;
        return;
    }
    const int j = bid - ZPAD_BLKS - CASTX_BLKS;
    const int which = j / WCAST_BLKS;
    const int idx = (j - which * WCAST_BLKS) * 256 + tid;   // (co, ci-octet)
    const float* w = which == 0 ? w1 : which == 1 ? w2 : which == 2 ? w3 : w4;
    unsigned short* gg = which == 0 ? o1 : which == 1 ? o2 : which == 2 ? o3 : o4;
    const int CI = (which == 0 || which == 2) ? DM : DC;
    const int OCT = CI / 8;
    const int co = idx / OCT, ci0 = (idx - co * OCT) * 8;
    const float4* p4 = reinterpret_cast<const float4*>(w + (size_t)(co * CI + ci0) * 3);
    float v[24];
#pragma unroll
    for (int q = 0; q < 6; ++q) *reinterpret_cast<float4*>(&v[q * 4]) = p4[q];
    unsigned short tmp[3][8];
#pragma unroll
    for (int e = 0; e < 24; ++e) tmp[e % 3][e / 3] = f2bf(v[e]);
    unsigned short* ob = gg + (size_t)co * (3 * CI) + ci0;
#pragma unroll
    for (int t = 0; t < 3; ++t)
        *reinterpret_cast<uint4*>(ob + (size_t)t * CI) = *reinterpret_cast<const uint4*>(tmp[t]);
}

// ---------------------------------------------------------------- conv1/3: BARRIER-FREE wave-private MFMA GEMM
// Each wave owns a 64x64 output tile and a private 32KB LDS region (2 bufs of
// A[64rows][64k] + B[64][64k], bf16). K = 3*CI linearized: K-tile kt (BK=64) lies
// entirely in tap t = kt/6 (CI=384=6*64), so A staging is just a row-shift — no
// im2col, no tap loop. Per-wave counted-vmcnt 2-deep pipeline (R7-proven protocol,
// now wave-local): vmcnt(16) -> 16 ds_read_b128 + 32 MFMA -> lgkmcnt(0) -> stage kt+2.
// ZERO s_barriers. XOR chunk-swizzle (chunk ^= row&7, both staged source and read
// slot) -> 2-way banks = free. Final vmcnt(0) so dead wrap-DMA can't write LDS
// after block retirement. 4 waves/block share the A panel (L1/L2-hot re-reads).

template <int CI, int CO>
__global__ __launch_bounds__(256, 1) void conv_wave_kernel(const unsigned short* __restrict__ in,
                                                           const unsigned short* __restrict__ wg,
                                                           const float* __restrict__ bias,
                                                           unsigned short* __restrict__ out) {
    constexpr int K3 = 3 * CI;              // 1152
    constexpr int NKT = K3 / 64;            // 18
    constexpr int KPT = CI / 64;            // 6 K-tiles per tap
    constexpr int NTG = CO / 256;           // 6 n-groups (4 waves x 64 cols)
    constexpr int NCONV = (NB * LIN / 64) * NTG;   // 768

    __shared__ __align__(16) unsigned short smem[65536];   // 128 KB

    const int tid = threadIdx.x, lane = tid & 63, wv = tid >> 6;

    // bijective XCD-chunk swizzle (m204); NCONV % 8 == 0
    const int orig = blockIdx.x;
    const int q = NCONV >> 3, xcd = orig & 7, o = orig >> 3;
    const int wgid = xcd * q + o;

    const int mt = wgid / NTG, ng = wgid - mt * NTG;
    const int b = mt >> 3, tm = mt & 7;     // batch, m-tile within batch (8 x 64 rows)
    const int n0 = ng * 256 + wv * 64;      // this wave's output columns

    const unsigned short* aTile = in + ((size_t)b * (LIN + 2) + (size_t)tm * 64) * CI;
    const unsigned short* bTile = wg + (size_t)n0 * K3;

    const int lrow8 = lane >> 3;            // staging row-in-group (8 rows/instr)
    const int lch = lane & 7;               // staging 16B chunk slot
    const int swz = (lch ^ lrow8) * 8;      // pre-swizzled source chunk (elements)
    const int fr = lane & 15, kg = lane >> 4;

    unsigned short* myA = smem + wv * 16384;   // per-wave 32KB region (ushort units)

    f32x4 acc[4][4];
#pragma unroll
    for (int m = 0; m < 4; ++m)
#pragma unroll
        for (int n = 0; n < 4; ++n) acc[m][n] = (f32x4){0.f, 0.f, 0.f, 0.f};

#define STG(d, kt)                                                                        \
    do {                                                                                  \
        const int t_ = (kt) / KPT, kc_ = (kt) - t_ * KPT;                                 \
        const unsigned short* ga = aTile + (size_t)(t_ + lrow8) * CI + kc_ * 64 + swz;    \
        unsigned short* la = myA + (d) * 8192;                                            \
        _Pragma("unroll")                                                                 \
        for (int g = 0; g < 8; ++g)                                                       \
            GL2LDS(ga + (size_t)(g * 8) * CI, la + g * 512);                              \
        const unsigned short* gb = bTile + (size_t)lrow8 * K3 + (kt) * 64 + swz;          \
        unsigned short* lb = la + 4096;                                                   \
        _Pragma("unroll")                                                                 \
        for (int g = 0; g < 8; ++g)                                                       \
            GL2LDS(gb + (size_t)(g * 8) * K3, lb + g * 512);                              \
    } while (0)

#define CMP(d)                                                                            \
    do {                                                                                  \
        const unsigned short* la = myA + (d) * 8192;                                      \
        bf16x8 aF[4][2], bF[4][2];                                                        \
        _Pragma("unroll")                                                                 \
        for (int m = 0; m < 4; ++m)                                                       \
            _Pragma("unroll")                                                             \
            for (int kh = 0; kh < 2; ++kh) {                                              \
                const int r = m * 16 + fr;                                                \
                aF[m][kh] = *reinterpret_cast<const bf16x8*>(                             \
                    &la[r * 64 + (((kh * 4 + kg) ^ (r & 7)) * 8)]);                       \
            }                                                                             \
        _Pragma("unroll")                                                                 \
        for (int n = 0; n < 4; ++n)                                                       \
            _Pragma("unroll")                                                             \
            for (int kh = 0; kh < 2; ++kh) {                                              \
                const int r = n * 16 + fr;                                                \
                bF[n][kh] = *reinterpret_cast<const bf16x8*>(                             \
                    &la[4096 + r * 64 + (((kh * 4 + kg) ^ (r & 7)) * 8)]);                \
            }                                                                             \
        _Pragma("unroll")                                                                 \
        for (int m = 0; m < 4; ++m)                                                       \
            _Pragma("unroll")                                                             \
            for (int n = 0; n < 4; ++n) {                                                 \
                acc[m][n] = __builtin_amdgcn_mfma_f32_16x16x32_bf16(aF[m][0], bF[n][0],   \
                                                                    acc[m][n], 0, 0, 0);  \
                acc[m][n] = __builtin_amdgcn_mfma_f32_16x16x32_bf16(aF[m][1], bF[n][1],   \
                                                                    acc[m][n], 0, 0, 0);  \
            }                                                                             \
    } while (0)

    // ---- wave-private 2-deep counted-vmcnt pipeline, no barriers
    STG(0, 0);
    STG(1, 1);
#pragma unroll 1
    for (int kt = 0; kt < NKT; ++kt) {
        const int d = kt & 1;
        asm volatile("s_waitcnt vmcnt(16)" ::: "memory");   // oldest batch landed
        CMP(d);
        asm volatile("s_waitcnt lgkmcnt(0)" ::: "memory");  // my reads done before re-stage
        int nk = kt + 2;
        if (nk >= NKT) nk -= NKT;                           // tail wrap (dead, uniform)
        STG(d, nk);
    }
#undef STG
#undef CMP
    asm volatile("s_waitcnt vmcnt(0)" ::: "memory");        // drain dead DMA before retire

    // epilogue: bias + ReLU -> bf16; C/D layout col=lane&15, row=(lane>>4)*4+reg
    const int fq = lane >> 4;
    float bv[4];
#pragma unroll
    for (int n = 0; n < 4; ++n) bv[n] = bias[n0 + n * 16 + fr];
    unsigned short* outb = out + ((size_t)b * (LIN + 2) + (size_t)tm * 64 + 1) * CO;
#pragma unroll
    for (int m = 0; m < 4; ++m)
#pragma unroll
        for (int qy = 0; qy < 4; ++qy) {
            unsigned short* orow = outb + (size_t)(m * 16 + fq * 4 + qy) * CO + n0 + fr;
#pragma unroll
            for (int n = 0; n < 4; ++n) {
                const float v = fmaxf(acc[m][n][qy] + bv[n], 0.f);
                orow[n * 16] = f2bf(v);
            }
        }
}

// ---------------------------------------------------------------- conv2/4: R12 2-phase counted-vmcnt kernel

template <int CI, int CO, int BN>
__global__ __launch_bounds__(256, 2) void conv_mfma_kernel(const unsigned short* __restrict__ in,
                                                           const unsigned short* __restrict__ wg,
                                                           const float* __restrict__ bias,
                                                           unsigned short* __restrict__ out) {
    constexpr int BM = 128, BK = 32;
    constexpr int KC = CI / BK;
    constexpr int AGRP_REAL = 9;
    constexpr int AGRP = 12;
    constexpr int GPT = BN / 16;
    constexpr int BGRP = 3 * GPT;
    constexpr int NW_N = BN / 32;
    constexpr int NT = CO / BN;
    constexpr int NCONV = NB * (LIN / BM) * NT;

    __shared__ __align__(16) unsigned short As[2][AGRP * 512];
    __shared__ __align__(16) unsigned short Bs[2][BGRP * 512];

    const int tid = threadIdx.x;
    const int lane = tid & 63;
    const int wv = tid >> 6;

    const int orig = blockIdx.x;
    const int q = NCONV >> 3, xcd = orig & 7, o = orig >> 3;
    const int wgid = xcd * q + o;

    const int mg = wgid / NT;
    const int nt = wgid - mg * NT;
    const int b = mg >> 2;
    const int l0 = (mg & 3) * BM;
    const int n0 = nt * BN;

    const int wr = wv >> 1, wc = wv & 1;

    const unsigned short* inb = in + (size_t)b * (LIN + 2) * CI;

    f32x4 acc[4][NW_N];
#pragma unroll
    for (int m = 0; m < 4; ++m)
#pragma unroll
        for (int n = 0; n < NW_N; ++n) acc[m][n] = (f32x4){0.f, 0.f, 0.f, 0.f};

    const int lrow = lane >> 2;
    const int lch = lane & 3;
    const int fr = lane & 15, kg = lane >> 4;

    const unsigned short* aroot = inb + (size_t)l0 * CI + lch * 8;
    const unsigned short* broot = wg + (size_t)n0 * (3 * CI) + lch * 8;

#define STAGE(c, kb)                                                                      \
    do {                                                                                  \
        const unsigned short* abase = aroot + (kb) * BK;                                  \
        _Pragma("unroll")                                                                 \
        for (int g = wv; g < AGRP; g += 4) {                                              \
            const int sg = g < AGRP_REAL ? g : 0;                                         \
            GL2LDS(abase + (size_t)(sg * 16 + lrow) * CI, &As[c][g * 512]);               \
        }                                                                                 \
        const unsigned short* bbase = broot + (kb) * BK;                                  \
        _Pragma("unroll")                                                                 \
        for (int g2 = wv; g2 < BGRP; g2 += 4) {                                           \
            const int t = g2 / GPT, gr = g2 - t * GPT;                                    \
            GL2LDS(bbase + (size_t)(gr * 16 + lrow) * (3 * CI) + (size_t)t * CI,          \
                   &Bs[c][g2 * 512]);                                                     \
        }                                                                                 \
    } while (0)

#define COMPUTE(c)                                                                        \
    do {                                                                                  \
        _Pragma("unroll")                                                                 \
        for (int t = 0; t < 3; ++t) {                                                     \
            bf16x8 aF[4], bF[NW_N];                                                       \
            _Pragma("unroll")                                                             \
            for (int m = 0; m < 4; ++m)                                                   \
                aF[m] = *reinterpret_cast<const bf16x8*>(                                 \
                    &As[c][(t + wr * 64 + m * 16 + fr) * BK + kg * 8]);                   \
            _Pragma("unroll")                                                             \
            for (int n = 0; n < NW_N; ++n)                                                \
                bF[n] = *reinterpret_cast<const bf16x8*>(                                 \
                    &Bs[c][(t * BN + wc * (BN / 2) + n * 16 + fr) * BK + kg * 8]);        \
            _Pragma("unroll")                                                             \
            for (int m = 0; m < 4; ++m)                                                   \
                _Pragma("unroll")                                                         \
                for (int n = 0; n < NW_N; ++n)                                            \
                    acc[m][n] =                                                           \
                        __builtin_amdgcn_mfma_f32_16x16x32_bf16(aF[m], bF[n], acc[m][n],  \
                                                                0, 0, 0);                 \
        }                                                                                 \
    } while (0)

#define WAITV                                                                             \
    do {                                                                                  \
        if constexpr (BN == 128)                                                          \
            asm volatile("s_waitcnt vmcnt(9)" ::: "memory");                              \
        else                                                                              \
            asm volatile("s_waitcnt vmcnt(6)" ::: "memory");                              \
    } while (0)

    STAGE(0, 0);
    STAGE(1, 1);
#pragma unroll 1
    for (int kb = 0; kb < KC; ++kb) {
        const int cur = kb & 1;
        WAITV;
        asm volatile("s_barrier" ::: "memory");
        COMPUTE(cur);
        asm volatile("s_waitcnt lgkmcnt(0)" ::: "memory");
        asm volatile("s_barrier" ::: "memory");
        int nk = kb + 2;
        if (nk >= KC) nk -= KC;
        STAGE(cur, nk);
    }
#undef STAGE
#undef COMPUTE
#undef WAITV

    const int fq = lane >> 4;
    float bv[NW_N];
#pragma unroll
    for (int n = 0; n < NW_N; ++n) bv[n] = bias[n0 + wc * (BN / 2) + n * 16 + fr];
    unsigned short* outb = out + (size_t)b * (LIN + 2) * CO;
#pragma unroll
    for (int m = 0; m < 4; ++m)
#pragma unroll
        for (int qy = 0; qy < 4; ++qy) {
            const int grow = l0 + wr * 64 + m * 16 + fq * 4 + qy + 1;
            unsigned short* orow = outb + (size_t)grow * CO + n0 + wc * (BN / 2) + fr;
#pragma unroll
            for (int n = 0; n < NW_N; ++n) {
                const float v = fmaxf(acc[m][n][qy] + bv[n], 0.f);
                orow[n * 16] = f2bf(v);
            }
        }
}

// ---------------------------------------------------------------- LayerNorm over bf16 padded buffer (in place)

__global__ void ln_kernel(unsigned short* __restrict__ h, const float* __restrict__ g,
                          const float* __restrict__ be) {
    const int row = blockIdx.x, lane = threadIdx.x;
    const int b = row >> 9, l = row & (LIN - 1);
    unsigned short* hr = h + ((size_t)b * (LIN + 2) + l + 1) * DM;
    float v[6];
    float s = 0.f;
#pragma unroll
    for (int j = 0; j < 6; ++j) { v[j] = bf2f(hr[lane + 64 * j]); s += v[j]; }
    s = wred(s);
    const float mean = s * (1.f / DM);
    float vs = 0.f;
#pragma unroll
    for (int j = 0; j < 6; ++j) { const float d = v[j] - mean; vs += d * d; }
    vs = wred(vs);
    const float rstd = rsqrtf(vs * (1.f / DM) + LN_EPS);
#pragma unroll
    for (int j = 0; j < 6; ++j) {
        const int c = lane + 64 * j;
        hr[c] = f2bf((v[j] - mean) * rstd * g[c] + be[c]);
    }
}

// ---------------------------------------------------------------- LayerNorm + linear(384->1), bf16 in, f32 out

__global__ void ln_linear_kernel(const unsigned short* __restrict__ h, const float* __restrict__ g,
                                 const float* __restrict__ be, const float* __restrict__ wl,
                                 const float* __restrict__ bl, float* __restrict__ dur) {
    const int row = blockIdx.x, lane = threadIdx.x;
    const int b = row >> 9, l = row & (LIN - 1);
    const unsigned short* hr = h + ((size_t)b * (LIN + 2) + l + 1) * DM;
    float v[6];
    float s = 0.f;
#pragma unroll
    for (int j = 0; j < 6; ++j) { v[j] = bf2f(hr[lane + 64 * j]); s += v[j]; }
    s = wred(s);
    const float mean = s * (1.f / DM);
    float vs = 0.f;
#pragma unroll
    for (int j = 0; j < 6; ++j) { const float d = v[j] - mean; vs += d * d; }
    vs = wred(vs);
    const float rstd = rsqrtf(vs * (1.f / DM) + LN_EPS);
    float dot = 0.f;
#pragma unroll
    for (int j = 0; j < 6; ++j) {
        const int c = lane + 64 * j;
        dot += ((v[j] - mean) * rstd * g[c] + be[c]) * wl[c];
    }
    dot = wred(dot);
    if (lane == 0) dur[row] = dot + bl[0];
}

// ---------------------------------------------------------------- launch

extern "C" void kernel_launch(void* const* d_in, const int* in_sizes, int n_in,
                              void* d_out, int out_size, void* d_ws, size_t ws_size,
                              hipStream_t stream) {
    const float* x   = (const float*)d_in[0];
    const int*   tgt = (const int*)d_in[1];
    const float* w1  = (const float*)d_in[3];
    const float* b1  = (const float*)d_in[4];
    const float* w2  = (const float*)d_in[5];
    const float* b2  = (const float*)d_in[6];
    const float* g1  = (const float*)d_in[7];
    const float* be1 = (const float*)d_in[8];
    const float* w3  = (const float*)d_in[9];
    const float* b3  = (const float*)d_in[10];
    const float* w4  = (const float*)d_in[11];
    const float* b4  = (const float*)d_in[12];
    const float* g2  = (const float*)d_in[13];
    const float* be2 = (const float*)d_in[14];
    const float* wl  = (const float*)d_in[15];
    const float* bl  = (const float*)d_in[16];

    float* out = (float*)d_out;                         // (16, 4096, 384) f32
    float* dur = out + (size_t)NB * MELMAX * DM;        // (16, 512) f32

    unsigned short* ws = (unsigned short*)d_ws;
    unsigned short* xb   = ws;                                 // (16, 514, 384)  also conv4 out
    unsigned short* hbig = xb + (size_t)NB * (LIN + 2) * DM;   // (16, 514, 1536) conv1/conv3 out
    unsigned short* h2b  = hbig + (size_t)NB * (LIN + 2) * DC; // (16, 514, 384)  conv2 out
    unsigned short* wg1  = h2b + (size_t)NB * (LIN + 2) * DM;  // (1536, 1152)
    unsigned short* wg2  = wg1 + (size_t)DC * 3 * DM;          // (384, 4608)
    unsigned short* wg3  = wg2 + (size_t)DM * 3 * DC;          // (1536, 1152)
    unsigned short* wg4  = wg3 + (size_t)DC * 3 * DM;          // (384, 4608)
    int* cum = (int*)(wg4 + (size_t)DM * 3 * DC);              // (16, 512)

    // ---- output 0: length regulate (standalone — fusion measured slower, R5/R6)
    cumsum_kernel<<<NB, LIN, 0, stream>>>(tgt, cum);
    gather_kernel<<<(NB * MELMAX) / 4, 256, 0, stream>>>(x, cum, out);

    // ---- prep (fused launch; coalesced wcast)
    prep_kernel<<<ZPAD_BLKS + CASTX_BLKS + 4 * WCAST_BLKS, 256, 0, stream>>>(
        x, xb, hbig, h2b, w1, w2, w3, w4, wg1, wg2, wg3, wg4);

    // ---- output 1: duration predictor
    // conv1/3: barrier-free wave-private kernel (768 blocks x 4 private 64x64 waves)
    // conv2/4: R12 2-phase counted-vmcnt kernel
    conv_wave_kernel<DM, DC><<<(NB * LIN / 64) * (DC / 256), 256, 0, stream>>>(xb, wg1, b1, hbig);
    conv_mfma_kernel<DC, DM, 64><<<NB * (LIN / 128) * (DM / 64), 256, 0, stream>>>(hbig, wg2, b2, h2b);
    ln_kernel<<<NB * LIN, 64, 0, stream>>>(h2b, g1, be1);
    conv_wave_kernel<DM, DC><<<(NB * LIN / 64) * (DC / 256), 256, 0, stream>>>(h2b, wg3, b3, hbig);
    conv_mfma_kernel<DC, DM, 64><<<NB * (LIN / 128) * (DM / 64), 256, 0, stream>>>(hbig, wg4, b4, xb);
    ln_linear_kernel<<<NB * LIN, 64, 0, stream>>>(xb, g2, be2, wl, bl, dur);
}

// Round 14
// 226.517 us; speedup vs baseline: 1.0201x; 1.0201x over previous
//
#include <hip/hip_runtime.h>
#include <hip/hip_bf16.h>
#include <cstddef>
#include <cstdint>

#define NB 16
#define LIN 512
#define DM 384
#define DC 1536
#define MELMAX 4096
#define LN_EPS 1e-5f

typedef __bf16 bf16x8 __attribute__((ext_vector_type(8)));
typedef float f32x4 __attribute__((ext_vector_type(4)));

#define GL2LDS(gp, lp)                                                                \
    __builtin_amdgcn_global_load_lds((const __attribute__((address_space(1))) void*)(gp), \
                                     (__attribute__((address_space(3))) void*)(lp), 16, 0, 0)

__device__ __forceinline__ float wred(float v) {
#pragma unroll
    for (int m = 32; m >= 1; m >>= 1) v += __shfl_xor(v, m, 64);
    return v;
}

__device__ __forceinline__ unsigned short f2bf(float f) {
    __hip_bfloat16 h = __float2bfloat16(f);
    return *reinterpret_cast<unsigned short*>(&h);
}

__device__ __forceinline__ float bf2f(unsigned short u) {
    return __uint_as_float(((unsigned)u) << 16);
}

// ---------------------------------------------------------------- cumsum (per batch, Hillis-Steele)

__global__ void cumsum_kernel(const int* __restrict__ tgt, int* __restrict__ cum) {
    __shared__ int s[LIN];
    const int b = blockIdx.x, tid = threadIdx.x;
    s[tid] = tgt[b * LIN + tid];
    __syncthreads();
    for (int off = 1; off < LIN; off <<= 1) {
        int v = (tid >= off) ? s[tid - off] : 0;
        __syncthreads();
        s[tid] += v;
        __syncthreads();
    }
    cum[b * LIN + tid] = s[tid];
}

// ---------------------------------------------------------------- length-regulate gather (standalone)

__global__ __launch_bounds__(256) void gather_kernel(const float* __restrict__ x,
                                                     const int* __restrict__ cum,
                                                     float* __restrict__ out) {
    const int wid = (blockIdx.x * 256 + threadIdx.x) >> 6;
    const int lane = threadIdx.x & 63;
    const int b = wid >> 12;
    const int t = wid & (MELMAX - 1);
    const int* c = cum + b * LIN;
    const int total = c[LIN - 1];
    float4* orow = reinterpret_cast<float4*>(out + ((size_t)b * MELMAX + t) * DM);
    if (t < total) {
        int lo = 0, hi = LIN;
        while (lo < hi) { int mid = (lo + hi) >> 1; if (c[mid] > t) hi = mid; else lo = mid + 1; }
        const int idx = lo < (LIN - 1) ? lo : (LIN - 1);
        const float4* xrow = reinterpret_cast<const float4*>(x + ((size_t)b * LIN + idx) * DM);
#pragma unroll
        for (int j = 0; j < 2; ++j) {
            const int p = lane + 64 * j;
            if (p < DM / 4) orow[p] = xrow[p];
        }
    } else {
        const float4 z = make_float4(0.f, 0.f, 0.f, 0.f);
#pragma unroll
        for (int j = 0; j < 2; ++j) {
            const int p = lane + 64 * j;
            if (p < DM / 4) orow[p] = z;
        }
    }
}

// ---------------------------------------------------------------- fused prep: zpad + cast_x + wcast (one launch)

#define ZPAD_BLKS 96
#define CASTX_BLKS 3072   // NB*LIN*DM/4/256
#define WCAST_BLKS 288    // DC*DM/8/256 per matrix

__global__ void prep_kernel(const float* __restrict__ x, unsigned short* __restrict__ xb,
                            unsigned short* __restrict__ hbig, unsigned short* __restrict__ h2b,
                            const float* __restrict__ w1, const float* __restrict__ w2,
                            const float* __restrict__ w3, const float* __restrict__ w4,
                            unsigned short* __restrict__ o1, unsigned short* __restrict__ o2,
                            unsigned short* __restrict__ o3, unsigned short* __restrict__ o4) {
    const int bid = blockIdx.x, tid = threadIdx.x;
    if (bid < ZPAD_BLKS) {
        const int buf = bid >> 5, rem = bid & 31;
        const int b = rem >> 1, row = (rem & 1) ? (LIN + 1) : 0;
        unsigned short* p = buf == 0 ? xb : (buf == 1 ? hbig : h2b);
        const int rl = buf == 1 ? DC : DM;
        unsigned short* base = p + ((size_t)b * (LIN + 2) + row) * rl;
        for (int c = tid; c < rl; c += 256) base[c] = 0;
        return;
    }
    if (bid < ZPAD_BLKS + CASTX_BLKS) {
        const int idx = (bid - ZPAD_BLKS) * 256 + tid;
        const float4 v = reinterpret_cast<const float4*>(x)[idx];
        const int e = idx * 4;
        const int b = e / (LIN * DM);
        const int rem = e - b * (LIN * DM);
        const int l = rem / DM;
        const int c = rem - l * DM;
        ushort4 o;
        o.x = f2bf(v.x); o.y = f2bf(v.y); o.z = f2bf(v.z); o.w = f2bf(v.w);
        *reinterpret_cast<ushort4*>(xb + ((size_t)b * (LIN + 2) + l + 1) * DM + c) = o;
        return;
    }
    const int j = bid - ZPAD_BLKS - CASTX_BLKS;
    const int which = j / WCAST_BLKS;
    const int idx = (j - which * WCAST_BLKS) * 256 + tid;   // (co, ci-octet)
    const float* w = which == 0 ? w1 : which == 1 ? w2 : which == 2 ? w3 : w4;
    unsigned short* gg = which == 0 ? o1 : which == 1 ? o2 : which == 2 ? o3 : o4;
    const int CI = (which == 0 || which == 2) ? DM : DC;
    const int OCT = CI / 8;
    const int co = idx / OCT, ci0 = (idx - co * OCT) * 8;
    const float4* p4 = reinterpret_cast<const float4*>(w + (size_t)(co * CI + ci0) * 3);
    float v[24];
#pragma unroll
    for (int q = 0; q < 6; ++q) *reinterpret_cast<float4*>(&v[q * 4]) = p4[q];
    unsigned short tmp[3][8];
#pragma unroll
    for (int e = 0; e < 24; ++e) tmp[e % 3][e / 3] = f2bf(v[e]);
    unsigned short* ob = gg + (size_t)co * (3 * CI) + ci0;
#pragma unroll
    for (int t = 0; t < 3; ++t)
        *reinterpret_cast<uint4*>(ob + (size_t)t * CI) = *reinterpret_cast<const uint4*>(tmp[t]);
}

// ---------------------------------------------------------------- conv1d(k=3,SAME) as bf16 MFMA GEMM
// DEPTH-3 counted-vmcnt pipeline (m218's full recipe: ~3 batches in flight).
// The buffer consumed at phase k was staged at phase k-3: two full phases of
// compute cover the L2/HBM return latency (depth-2 covered only one — the
// constant exposed-latency term that produced the 58µs plateau, R7-R13).
// BM=128, BN=64, BK=32 for ALL convs; LDS 3 x (A 12KB + B 12KB) = 72KB ->
// 2 blocks/CU. Per-wave stage batch = 3A + 3B = 6 loads -> phase-top
// s_waitcnt vmcnt(12) (two newer batches stay in flight). Barriers are plain
// memory-fences (R12). Wrap-staging keeps counts uniform; final vmcnt(0).

template <int CI, int CO>
__global__ __launch_bounds__(256, 2) void conv_mfma_kernel(const unsigned short* __restrict__ in,
                                                           const unsigned short* __restrict__ wg,
                                                           const float* __restrict__ bias,
                                                           unsigned short* __restrict__ out) {
    constexpr int BM = 128, BN = 64, BK = 32;
    constexpr int KC = CI / BK;             // 12 or 48 (divisible by 3)
    constexpr int AGRP_REAL = 9;            // 144 staged rows (need BM+2)
    constexpr int AGRP = 12;                // padded -> exactly 3 A-loads per wave
    constexpr int GPT = BN / 16;            // 4 row-groups per B tap tile
    constexpr int BGRP = 3 * GPT;           // 12 -> 3 B-loads per wave
    constexpr int NW_N = BN / 32;           // 2
    constexpr int NT = CO / BN;
    constexpr int NCONV = NB * (LIN / BM) * NT;

    __shared__ __align__(16) unsigned short As[3][AGRP * 512];
    __shared__ __align__(16) unsigned short Bs[3][BGRP * 512];

    const int tid = threadIdx.x;
    const int lane = tid & 63;
    const int wv = tid >> 6;

    // bijective XCD-chunk swizzle (m204); NCONV % 8 == 0
    const int orig = blockIdx.x;
    const int q = NCONV >> 3, xcd = orig & 7, o = orig >> 3;
    const int wgid = xcd * q + o;

    const int mg = wgid / NT;               // m-tile (n fastest)
    const int nt = wgid - mg * NT;
    const int b = mg >> 2;                  // LIN/BM == 4
    const int l0 = (mg & 3) * BM;
    const int n0 = nt * BN;

    const int wr = wv >> 1, wc = wv & 1;    // 2x2 wave grid, wave tile 64x32

    const unsigned short* inb = in + (size_t)b * (LIN + 2) * CI;

    f32x4 acc[4][NW_N];
#pragma unroll
    for (int m = 0; m < 4; ++m)
#pragma unroll
        for (int n = 0; n < NW_N; ++n) acc[m][n] = (f32x4){0.f, 0.f, 0.f, 0.f};

    const int lrow = lane >> 2;             // 0..15
    const int lch = lane & 3;               // 16B chunk
    const int fr = lane & 15, kg = lane >> 4;

    const unsigned short* aroot = inb + (size_t)l0 * CI + lch * 8;
    const unsigned short* broot = wg + (size_t)n0 * (3 * CI) + lch * 8;

#define STAGE(c, kb)                                                                      \
    do {                                                                                  \
        const unsigned short* abase = aroot + (kb) * BK;                                  \
        _Pragma("unroll")                                                                 \
        for (int g = wv; g < AGRP; g += 4) {                                              \
            const int sg = g < AGRP_REAL ? g : 0; /* pad groups: dead reload of group 0 */\
            GL2LDS(abase + (size_t)(sg * 16 + lrow) * CI, &As[c][g * 512]);               \
        }                                                                                 \
        const unsigned short* bbase = broot + (kb) * BK;                                  \
        _Pragma("unroll")                                                                 \
        for (int g2 = wv; g2 < BGRP; g2 += 4) {                                           \
            const int t = g2 / GPT, gr = g2 - t * GPT;                                    \
            GL2LDS(bbase + (size_t)(gr * 16 + lrow) * (3 * CI) + (size_t)t * CI,          \
                   &Bs[c][g2 * 512]);                                                     \
        }                                                                                 \
    } while (0)

#define COMPUTE(c)                                                                        \
    do {                                                                                  \
        _Pragma("unroll")                                                                 \
        for (int t = 0; t < 3; ++t) {                                                     \
            bf16x8 aF[4], bF[NW_N];                                                       \
            _Pragma("unroll")                                                             \
            for (int m = 0; m < 4; ++m)                                                   \
                aF[m] = *reinterpret_cast<const bf16x8*>(                                 \
                    &As[c][(t + wr * 64 + m * 16 + fr) * BK + kg * 8]);                   \
            _Pragma("unroll")                                                             \
            for (int n = 0; n < NW_N; ++n)                                                \
                bF[n] = *reinterpret_cast<const bf16x8*>(                                 \
                    &Bs[c][(t * BN + wc * (BN / 2) + n * 16 + fr) * BK + kg * 8]);        \
            _Pragma("unroll")                                                             \
            for (int m = 0; m < 4; ++m)                                                   \
                _Pragma("unroll")                                                         \
                for (int n = 0; n < NW_N; ++n)                                            \
                    acc[m][n] =                                                           \
                        __builtin_amdgcn_mfma_f32_16x16x32_bf16(aF[m], bF[n], acc[m][n],  \
                                                                0, 0, 0);                 \
        }                                                                                 \
    } while (0)

#define PHASE(c, k)                                                                       \
    do {                                                                                  \
        asm volatile("s_waitcnt vmcnt(12)" ::: "memory"); /* batch staged 3 phases ago */ \
        asm volatile("s_barrier" ::: "memory");           /* all waves' buf[c] landed */  \
        COMPUTE(c);                                                                       \
        asm volatile("s_waitcnt lgkmcnt(0)" ::: "memory");                                \
        asm volatile("s_barrier" ::: "memory");           /* everyone done with buf[c] */ \
        int nk = (k) + 3;                                                                 \
        if (nk >= KC) nk -= KC;                           /* tail wrap: dead, uniform */  \
        STAGE(c, nk);                                                                     \
    } while (0)

    // ---- depth-3 pipeline: 3 batches in flight from the start
    STAGE(0, 0);
    STAGE(1, 1);
    STAGE(2, 2);
#pragma unroll 1
    for (int kb = 0; kb < KC; kb += 3) {
        PHASE(0, kb);
        PHASE(1, kb + 1);
        PHASE(2, kb + 2);
    }
#undef STAGE
#undef COMPUTE
#undef PHASE
    asm volatile("s_waitcnt vmcnt(0)" ::: "memory");      // drain dead wrap-DMA

    // epilogue: bias + ReLU -> bf16; C/D layout col=lane&15, row=(lane>>4)*4+reg
    const int fq = lane >> 4;
    float bv[NW_N];
#pragma unroll
    for (int n = 0; n < NW_N; ++n) bv[n] = bias[n0 + wc * (BN / 2) + n * 16 + fr];
    unsigned short* outb = out + (size_t)b * (LIN + 2) * CO;
#pragma unroll
    for (int m = 0; m < 4; ++m)
#pragma unroll
        for (int qy = 0; qy < 4; ++qy) {
            const int grow = l0 + wr * 64 + m * 16 + fq * 4 + qy + 1;
            unsigned short* orow = outb + (size_t)grow * CO + n0 + wc * (BN / 2) + fr;
#pragma unroll
            for (int n = 0; n < NW_N; ++n) {
                const float v = fmaxf(acc[m][n][qy] + bv[n], 0.f);
                orow[n * 16] = f2bf(v);
            }
        }
}

// ---------------------------------------------------------------- LayerNorm over bf16 padded buffer (in place)

__global__ void ln_kernel(unsigned short* __restrict__ h, const float* __restrict__ g,
                          const float* __restrict__ be) {
    const int row = blockIdx.x, lane = threadIdx.x;
    const int b = row >> 9, l = row & (LIN - 1);
    unsigned short* hr = h + ((size_t)b * (LIN + 2) + l + 1) * DM;
    float v[6];
    float s = 0.f;
#pragma unroll
    for (int j = 0; j < 6; ++j) { v[j] = bf2f(hr[lane + 64 * j]); s += v[j]; }
    s = wred(s);
    const float mean = s * (1.f / DM);
    float vs = 0.f;
#pragma unroll
    for (int j = 0; j < 6; ++j) { const float d = v[j] - mean; vs += d * d; }
    vs = wred(vs);
    const float rstd = rsqrtf(vs * (1.f / DM) + LN_EPS);
#pragma unroll
    for (int j = 0; j < 6; ++j) {
        const int c = lane + 64 * j;
        hr[c] = f2bf((v[j] - mean) * rstd * g[c] + be[c]);
    }
}

// ---------------------------------------------------------------- LayerNorm + linear(384->1), bf16 in, f32 out

__global__ void ln_linear_kernel(const unsigned short* __restrict__ h, const float* __restrict__ g,
                                 const float* __restrict__ be, const float* __restrict__ wl,
                                 const float* __restrict__ bl, float* __restrict__ dur) {
    const int row = blockIdx.x, lane = threadIdx.x;
    const int b = row >> 9, l = row & (LIN - 1);
    const unsigned short* hr = h + ((size_t)b * (LIN + 2) + l + 1) * DM;
    float v[6];
    float s = 0.f;
#pragma unroll
    for (int j = 0; j < 6; ++j) { v[j] = bf2f(hr[lane + 64 * j]); s += v[j]; }
    s = wred(s);
    const float mean = s * (1.f / DM);
    float vs = 0.f;
#pragma unroll
    for (int j = 0; j < 6; ++j) { const float d = v[j] - mean; vs += d * d; }
    vs = wred(vs);
    const float rstd = rsqrtf(vs * (1.f / DM) + LN_EPS);
    float dot = 0.f;
#pragma unroll
    for (int j = 0; j < 6; ++j) {
        const int c = lane + 64 * j;
        dot += ((v[j] - mean) * rstd * g[c] + be[c]) * wl[c];
    }
    dot = wred(dot);
    if (lane == 0) dur[row] = dot + bl[0];
}

// ---------------------------------------------------------------- launch

extern "C" void kernel_launch(void* const* d_in, const int* in_sizes, int n_in,
                              void* d_out, int out_size, void* d_ws, size_t ws_size,
                              hipStream_t stream) {
    const float* x   = (const float*)d_in[0];
    const int*   tgt = (const int*)d_in[1];
    const float* w1  = (const float*)d_in[3];
    const float* b1  = (const float*)d_in[4];
    const float* w2  = (const float*)d_in[5];
    const float* b2  = (const float*)d_in[6];
    const float* g1  = (const float*)d_in[7];
    const float* be1 = (const float*)d_in[8];
    const float* w3  = (const float*)d_in[9];
    const float* b3  = (const float*)d_in[10];
    const float* w4  = (const float*)d_in[11];
    const float* b4  = (const float*)d_in[12];
    const float* g2  = (const float*)d_in[13];
    const float* be2 = (const float*)d_in[14];
    const float* wl  = (const float*)d_in[15];
    const float* bl  = (const float*)d_in[16];

    float* out = (float*)d_out;                         // (16, 4096, 384) f32
    float* dur = out + (size_t)NB * MELMAX * DM;        // (16, 512) f32

    unsigned short* ws = (unsigned short*)d_ws;
    unsigned short* xb   = ws;                                 // (16, 514, 384)  also conv4 out
    unsigned short* hbig = xb + (size_t)NB * (LIN + 2) * DM;   // (16, 514, 1536) conv1/conv3 out
    unsigned short* h2b  = hbig + (size_t)NB * (LIN + 2) * DC; // (16, 514, 384)  conv2 out
    unsigned short* wg1  = h2b + (size_t)NB * (LIN + 2) * DM;  // (1536, 1152)
    unsigned short* wg2  = wg1 + (size_t)DC * 3 * DM;          // (384, 4608)
    unsigned short* wg3  = wg2 + (size_t)DM * 3 * DC;          // (1536, 1152)
    unsigned short* wg4  = wg3 + (size_t)DC * 3 * DM;          // (384, 4608)
    int* cum = (int*)(wg4 + (size_t)DM * 3 * DC);              // (16, 512)

    // ---- output 0: length regulate (standalone — fusion measured slower, R5/R6)
    cumsum_kernel<<<NB, LIN, 0, stream>>>(tgt, cum);
    gather_kernel<<<(NB * MELMAX) / 4, 256, 0, stream>>>(x, cum, out);

    // ---- prep (fused launch; coalesced wcast)
    prep_kernel<<<ZPAD_BLKS + CASTX_BLKS + 4 * WCAST_BLKS, 256, 0, stream>>>(
        x, xb, hbig, h2b, w1, w2, w3, w4, wg1, wg2, wg3, wg4);

    // ---- output 1: duration predictor (bf16 MFMA convs, DEPTH-3 counted-vmcnt)
    conv_mfma_kernel<DM, DC><<<NB * (LIN / 128) * (DC / 64), 256, 0, stream>>>(xb, wg1, b1, hbig);
    conv_mfma_kernel<DC, DM><<<NB * (LIN / 128) * (DM / 64), 256, 0, stream>>>(hbig, wg2, b2, h2b);
    ln_kernel<<<NB * LIN, 64, 0, stream>>>(h2b, g1, be1);
    conv_mfma_kernel<DM, DC><<<NB * (LIN / 128) * (DC / 64), 256, 0, stream>>>(h2b, wg3, b3, hbig);
    conv_mfma_kernel<DC, DM><<<NB * (LIN / 128) * (DM / 64), 256, 0, stream>>>(hbig, wg4, b4, xb);
    ln_linear_kernel<<<NB * LIN, 64, 0, stream>>>(xb, g2, be2, wl, bl, dur);
}

// Round 15
// 220.715 us; speedup vs baseline: 1.0469x; 1.0263x over previous
//
#include <hip/hip_runtime.h>
#include <hip/hip_bf16.h>
#include <cstddef>
#include <cstdint>

#define NB 16
#define LIN 512
#define DM 384
#define DC 1536
#define MELMAX 4096
#define LN_EPS 1e-5f

typedef __bf16 bf16x8 __attribute__((ext_vector_type(8)));
typedef float f32x4 __attribute__((ext_vector_type(4)));

#define GL2LDS(gp, lp)                                                                \
    __builtin_amdgcn_global_load_lds((const __attribute__((address_space(1))) void*)(gp), \
                                     (__attribute__((address_space(3))) void*)(lp), 16, 0, 0)

__device__ __forceinline__ float wred(float v) {
#pragma unroll
    for (int m = 32; m >= 1; m >>= 1) v += __shfl_xor(v, m, 64);
    return v;
}

__device__ __forceinline__ unsigned short f2bf(float f) {
    __hip_bfloat16 h = __float2bfloat16(f);
    return *reinterpret_cast<unsigned short*>(&h);
}

__device__ __forceinline__ float bf2f(unsigned short u) {
    return __uint_as_float(((unsigned)u) << 16);
}

// ---------------------------------------------------------------- length-regulate gather (standalone)

__global__ __launch_bounds__(256) void gather_kernel(const float* __restrict__ x,
                                                     const int* __restrict__ cum,
                                                     float* __restrict__ out) {
    const int wid = (blockIdx.x * 256 + threadIdx.x) >> 6;
    const int lane = threadIdx.x & 63;
    const int b = wid >> 12;
    const int t = wid & (MELMAX - 1);
    const int* c = cum + b * LIN;
    const int total = c[LIN - 1];
    float4* orow = reinterpret_cast<float4*>(out + ((size_t)b * MELMAX + t) * DM);
    if (t < total) {
        int lo = 0, hi = LIN;
        while (lo < hi) { int mid = (lo + hi) >> 1; if (c[mid] > t) hi = mid; else lo = mid + 1; }
        const int idx = lo < (LIN - 1) ? lo : (LIN - 1);
        const float4* xrow = reinterpret_cast<const float4*>(x + ((size_t)b * LIN + idx) * DM);
#pragma unroll
        for (int j = 0; j < 2; ++j) {
            const int p = lane + 64 * j;
            if (p < DM / 4) orow[p] = xrow[p];
        }
    } else {
        const float4 z = make_float4(0.f, 0.f, 0.f, 0.f);
#pragma unroll
        for (int j = 0; j < 2; ++j) {
            const int p = lane + 64 * j;
            if (p < DM / 4) orow[p] = z;
        }
    }
}

// ---------------------------------------------------------------- fused prep: zpad + cast_x + wcast + cumsum

#define ZPAD_BLKS 96
#define CASTX_BLKS 3072   // NB*LIN*DM/4/256
#define WCAST_BLKS 288    // DC*DM/8/256 per matrix
#define PREP_TOTAL (ZPAD_BLKS + CASTX_BLKS + 4 * WCAST_BLKS + NB)

__global__ void prep_kernel(const float* __restrict__ x, unsigned short* __restrict__ xb,
                            unsigned short* __restrict__ hbig, unsigned short* __restrict__ h2b,
                            const float* __restrict__ w1, const float* __restrict__ w2,
                            const float* __restrict__ w3, const float* __restrict__ w4,
                            unsigned short* __restrict__ o1, unsigned short* __restrict__ o2,
                            unsigned short* __restrict__ o3, unsigned short* __restrict__ o4,
                            const int* __restrict__ tgt, int* __restrict__ cum) {
    const int bid = blockIdx.x, tid = threadIdx.x;
    if (bid < ZPAD_BLKS) {
        const int buf = bid >> 5, rem = bid & 31;
        const int b = rem >> 1, row = (rem & 1) ? (LIN + 1) : 0;
        unsigned short* p = buf == 0 ? xb : (buf == 1 ? hbig : h2b);
        const int rl = buf == 1 ? DC : DM;
        unsigned short* base = p + ((size_t)b * (LIN + 2) + row) * rl;
        for (int c = tid; c < rl; c += 256) base[c] = 0;
        return;
    }
    if (bid < ZPAD_BLKS + CASTX_BLKS) {
        const int idx = (bid - ZPAD_BLKS) * 256 + tid;
        const float4 v = reinterpret_cast<const float4*>(x)[idx];
        const int e = idx * 4;
        const int b = e / (LIN * DM);
        const int rem = e - b * (LIN * DM);
        const int l = rem / DM;
        const int c = rem - l * DM;
        ushort4 o;
        o.x = f2bf(v.x); o.y = f2bf(v.y); o.z = f2bf(v.z); o.w = f2bf(v.w);
        *reinterpret_cast<ushort4*>(xb + ((size_t)b * (LIN + 2) + l + 1) * DM + c) = o;
        return;
    }
    if (bid < ZPAD_BLKS + CASTX_BLKS + 4 * WCAST_BLKS) {
        const int j = bid - ZPAD_BLKS - CASTX_BLKS;
        const int which = j / WCAST_BLKS;
        const int idx = (j - which * WCAST_BLKS) * 256 + tid;   // (co, ci-octet)
        const float* w = which == 0 ? w1 : which == 1 ? w2 : which == 2 ? w3 : w4;
        unsigned short* gg = which == 0 ? o1 : which == 1 ? o2 : which == 2 ? o3 : o4;
        const int CI = (which == 0 || which == 2) ? DM : DC;
        const int OCT = CI / 8;
        const int co = idx / OCT, ci0 = (idx - co * OCT) * 8;
        const float4* p4 = reinterpret_cast<const float4*>(w + (size_t)(co * CI + ci0) * 3);
        float v[24];
#pragma unroll
        for (int q = 0; q < 6; ++q) *reinterpret_cast<float4*>(&v[q * 4]) = p4[q];
        unsigned short tmp[3][8];
#pragma unroll
        for (int e = 0; e < 24; ++e) tmp[e % 3][e / 3] = f2bf(v[e]);
        unsigned short* ob = gg + (size_t)co * (3 * CI) + ci0;
#pragma unroll
        for (int t = 0; t < 3; ++t)
            *reinterpret_cast<uint4*>(ob + (size_t)t * CI) = *reinterpret_cast<const uint4*>(tmp[t]);
        return;
    }
    // ---- cumsum: one block per batch (256 threads, 512 elems)
    {
        const int b = bid - (ZPAD_BLKS + CASTX_BLKS + 4 * WCAST_BLKS);
        __shared__ int s[LIN];
        s[tid] = tgt[b * LIN + tid];
        s[tid + 256] = tgt[b * LIN + tid + 256];
        __syncthreads();
        for (int off = 1; off < LIN; off <<= 1) {
            int v0 = (tid >= off) ? s[tid - off] : 0;
            int v1 = (tid + 256 >= off) ? s[tid + 256 - off] : 0;
            __syncthreads();
            s[tid] += v0;
            s[tid + 256] += v1;
            __syncthreads();
        }
        cum[b * LIN + tid] = s[tid];
        cum[b * LIN + tid + 256] = s[tid + 256];
    }
}

// ---------------------------------------------------------------- conv1d(k=3,SAME) as bf16 MFMA GEMM
// R7-exact: tap-merged A+B LDS staging, counted-vmcnt 2-deep pipeline (raw
// s_barrier, loads in flight across barriers, never vmcnt(0) in loop),
// XCD-chunked swizzle, sched_barrier-pinned protocol. Per-wave stage loads
// uniform: BN=128 -> A3+B6 -> vmcnt(9); BN=64 -> A3+B3 -> vmcnt(6).

template <int CI, int CO, int BN>
__global__ __launch_bounds__(256, 2) void conv_mfma_kernel(const unsigned short* __restrict__ in,
                                                           const unsigned short* __restrict__ wg,
                                                           const float* __restrict__ bias,
                                                           unsigned short* __restrict__ out) {
    constexpr int BM = 128, BK = 32;
    constexpr int KC = CI / BK;             // K-blocks (12 or 48, even)
    constexpr int AGRP = 12;                // padded (only first 9 carry real rows)
    constexpr int GPT = BN / 16;            // row-groups per B tap tile
    constexpr int BGRP = 3 * GPT;           // 24 (BN=128) / 12 (BN=64)
    constexpr int NW_N = BN / 32;           // n-frags per wave
    constexpr int NT = CO / BN;
    constexpr int NCONV = NB * (LIN / BM) * NT;

    __shared__ __align__(16) unsigned short As[2][AGRP * 512];
    __shared__ __align__(16) unsigned short Bs[2][BGRP * 512];

    const int tid = threadIdx.x;
    const int lane = tid & 63;
    const int wv = tid >> 6;

    // bijective XCD-chunk swizzle (m204); NCONV % 8 == 0
    const int orig = blockIdx.x;
    const int q = NCONV >> 3, xcd = orig & 7, o = orig >> 3;
    const int wgid = xcd * q + o;

    const int mg = wgid / NT;               // m-tile (n fastest)
    const int nt = wgid - mg * NT;
    const int b = mg >> 2;                  // LIN/BM == 4
    const int l0 = (mg & 3) * BM;
    const int n0 = nt * BN;

    const int wr = wv >> 1, wc = wv & 1;    // 2x2 wave grid

    const unsigned short* inb = in + (size_t)b * (LIN + 2) * CI;

    f32x4 acc[4][NW_N];
#pragma unroll
    for (int m = 0; m < 4; ++m)
#pragma unroll
        for (int n = 0; n < NW_N; ++n) acc[m][n] = (f32x4){0.f, 0.f, 0.f, 0.f};

    const int lrow = lane >> 2;             // 0..15
    const int lch = lane & 3;               // 16B chunk
    const int fr = lane & 15, kg = lane >> 4;

    const unsigned short* aroot = inb + (size_t)l0 * CI + lch * 8;
    const unsigned short* broot = wg + (size_t)n0 * (3 * CI) + lch * 8;

#define STAGE(c, kb)                                                                      \
    do {                                                                                  \
        const unsigned short* abase = aroot + (kb) * BK;                                  \
        _Pragma("unroll")                                                                 \
        for (int g = wv; g < AGRP; g += 4) {                                              \
            const int sg = g < 9 ? g : 0; /* pad groups reload row 0 (unused in LDS) */   \
            GL2LDS(abase + (size_t)(sg * 16 + lrow) * CI, &As[c][g * 512]);               \
        }                                                                                 \
        const unsigned short* bbase = broot + (kb) * BK;                                  \
        _Pragma("unroll")                                                                 \
        for (int g2 = wv; g2 < BGRP; g2 += 4) {                                           \
            const int t = g2 / GPT, gr = g2 - t * GPT;                                    \
            GL2LDS(bbase + (size_t)(gr * 16 + lrow) * (3 * CI) + (size_t)t * CI,          \
                   &Bs[c][g2 * 512]);                                                     \
        }                                                                                 \
    } while (0)

#define COMPUTE(c)                                                                        \
    do {                                                                                  \
        _Pragma("unroll")                                                                 \
        for (int t = 0; t < 3; ++t) {                                                     \
            bf16x8 aF[4], bF[NW_N];                                                       \
            _Pragma("unroll")                                                             \
            for (int m = 0; m < 4; ++m)                                                   \
                aF[m] = *reinterpret_cast<const bf16x8*>(                                 \
                    &As[c][(t + wr * 64 + m * 16 + fr) * BK + kg * 8]);                   \
            _Pragma("unroll")                                                             \
            for (int n = 0; n < NW_N; ++n)                                                \
                bF[n] = *reinterpret_cast<const bf16x8*>(                                 \
                    &Bs[c][(t * BN + wc * (BN / 2) + n * 16 + fr) * BK + kg * 8]);        \
            _Pragma("unroll")                                                             \
            for (int m = 0; m < 4; ++m)                                                   \
                _Pragma("unroll")                                                         \
                for (int n = 0; n < NW_N; ++n)                                            \
                    acc[m][n] =                                                           \
                        __builtin_amdgcn_mfma_f32_16x16x32_bf16(aF[m], bF[n], acc[m][n],  \
                                                                0, 0, 0);                 \
        }                                                                                 \
    } while (0)

    // ---- 2-deep counted-vmcnt pipeline (R7-exact)
    STAGE(0, 0);
    STAGE(1, 1);
#pragma unroll 1
    for (int kb = 0; kb < KC; ++kb) {
        const int cur = kb & 1;
        if constexpr (BN == 128)
            asm volatile("s_waitcnt vmcnt(9)" ::: "memory");
        else
            asm volatile("s_waitcnt vmcnt(6)" ::: "memory");
        __builtin_amdgcn_sched_barrier(0);
        __builtin_amdgcn_s_barrier();          // all waves' buf[cur] loads landed
        __builtin_amdgcn_sched_barrier(0);
        COMPUTE(cur);
        asm volatile("s_waitcnt lgkmcnt(0)" ::: "memory");  // my ds_reads of buf[cur] done
        __builtin_amdgcn_sched_barrier(0);
        __builtin_amdgcn_s_barrier();          // everyone done reading buf[cur]
        __builtin_amdgcn_sched_barrier(0);
        int nk = kb + 2;
        if (nk >= KC) nk -= KC;                // wrap keeps outstanding count uniform
        STAGE(cur, nk);
    }
#undef STAGE
#undef COMPUTE
    asm volatile("s_waitcnt vmcnt(0)" ::: "memory");        // drain dead wrap-DMA

    // epilogue: bias + ReLU -> bf16; C/D layout col=lane&15, row=(lane>>4)*4+reg
    const int fq = lane >> 4;
    float bv[NW_N];
#pragma unroll
    for (int n = 0; n < NW_N; ++n) bv[n] = bias[n0 + wc * (BN / 2) + n * 16 + fr];
    unsigned short* outb = out + (size_t)b * (LIN + 2) * CO;
#pragma unroll
    for (int m = 0; m < 4; ++m)
#pragma unroll
        for (int qy = 0; qy < 4; ++qy) {
            const int grow = l0 + wr * 64 + m * 16 + fq * 4 + qy + 1;
            unsigned short* orow = outb + (size_t)grow * CO + n0 + wc * (BN / 2) + fr;
#pragma unroll
            for (int n = 0; n < NW_N; ++n) {
                const float v = fmaxf(acc[m][n][qy] + bv[n], 0.f);
                orow[n * 16] = f2bf(v);
            }
        }
}

// ---------------------------------------------------------------- LayerNorm (4 rows per block, in place)

__global__ __launch_bounds__(256) void ln_kernel(unsigned short* __restrict__ h,
                                                 const float* __restrict__ g,
                                                 const float* __restrict__ be) {
    const int row = blockIdx.x * 4 + (threadIdx.x >> 6);
    const int lane = threadIdx.x & 63;
    const int b = row >> 9, l = row & (LIN - 1);
    unsigned short* hr = h + ((size_t)b * (LIN + 2) + l + 1) * DM;
    float v[6];
    float s = 0.f;
#pragma unroll
    for (int j = 0; j < 6; ++j) { v[j] = bf2f(hr[lane + 64 * j]); s += v[j]; }
    s = wred(s);
    const float mean = s * (1.f / DM);
    float vs = 0.f;
#pragma unroll
    for (int j = 0; j < 6; ++j) { const float d = v[j] - mean; vs += d * d; }
    vs = wred(vs);
    const float rstd = rsqrtf(vs * (1.f / DM) + LN_EPS);
#pragma unroll
    for (int j = 0; j < 6; ++j) {
        const int c = lane + 64 * j;
        hr[c] = f2bf((v[j] - mean) * rstd * g[c] + be[c]);
    }
}

// ---------------------------------------------------------------- LayerNorm + linear(384->1), 4 rows/block

__global__ __launch_bounds__(256) void ln_linear_kernel(const unsigned short* __restrict__ h,
                                                        const float* __restrict__ g,
                                                        const float* __restrict__ be,
                                                        const float* __restrict__ wl,
                                                        const float* __restrict__ bl,
                                                        float* __restrict__ dur) {
    const int row = blockIdx.x * 4 + (threadIdx.x >> 6);
    const int lane = threadIdx.x & 63;
    const int b = row >> 9, l = row & (LIN - 1);
    const unsigned short* hr = h + ((size_t)b * (LIN + 2) + l + 1) * DM;
    float v[6];
    float s = 0.f;
#pragma unroll
    for (int j = 0; j < 6; ++j) { v[j] = bf2f(hr[lane + 64 * j]); s += v[j]; }
    s = wred(s);
    const float mean = s * (1.f / DM);
    float vs = 0.f;
#pragma unroll
    for (int j = 0; j < 6; ++j) { const float d = v[j] - mean; vs += d * d; }
    vs = wred(vs);
    const float rstd = rsqrtf(vs * (1.f / DM) + LN_EPS);
    float dot = 0.f;
#pragma unroll
    for (int j = 0; j < 6; ++j) {
        const int c = lane + 64 * j;
        dot += ((v[j] - mean) * rstd * g[c] + be[c]) * wl[c];
    }
    dot = wred(dot);
    if (lane == 0) dur[row] = dot + bl[0];
}

// ---------------------------------------------------------------- launch

extern "C" void kernel_launch(void* const* d_in, const int* in_sizes, int n_in,
                              void* d_out, int out_size, void* d_ws, size_t ws_size,
                              hipStream_t stream) {
    const float* x   = (const float*)d_in[0];
    const int*   tgt = (const int*)d_in[1];
    const float* w1  = (const float*)d_in[3];
    const float* b1  = (const float*)d_in[4];
    const float* w2  = (const float*)d_in[5];
    const float* b2  = (const float*)d_in[6];
    const float* g1  = (const float*)d_in[7];
    const float* be1 = (const float*)d_in[8];
    const float* w3  = (const float*)d_in[9];
    const float* b3  = (const float*)d_in[10];
    const float* w4  = (const float*)d_in[11];
    const float* b4  = (const float*)d_in[12];
    const float* g2  = (const float*)d_in[13];
    const float* be2 = (const float*)d_in[14];
    const float* wl  = (const float*)d_in[15];
    const float* bl  = (const float*)d_in[16];

    float* out = (float*)d_out;                         // (16, 4096, 384) f32
    float* dur = out + (size_t)NB * MELMAX * DM;        // (16, 512) f32

    unsigned short* ws = (unsigned short*)d_ws;
    unsigned short* xb   = ws;                                 // (16, 514, 384)  also conv4 out
    unsigned short* hbig = xb + (size_t)NB * (LIN + 2) * DM;   // (16, 514, 1536) conv1/conv3 out
    unsigned short* h2b  = hbig + (size_t)NB * (LIN + 2) * DC; // (16, 514, 384)  conv2 out
    unsigned short* wg1  = h2b + (size_t)NB * (LIN + 2) * DM;  // (1536, 1152)
    unsigned short* wg2  = wg1 + (size_t)DC * 3 * DM;          // (384, 4608)
    unsigned short* wg3  = wg2 + (size_t)DM * 3 * DC;          // (1536, 1152)
    unsigned short* wg4  = wg3 + (size_t)DC * 3 * DM;          // (384, 4608)
    int* cum = (int*)(wg4 + (size_t)DM * 3 * DC);              // (16, 512)

    // ---- prep (zpad + cast_x + wcast + cumsum, one launch)
    prep_kernel<<<PREP_TOTAL, 256, 0, stream>>>(x, xb, hbig, h2b, w1, w2, w3, w4,
                                                wg1, wg2, wg3, wg4, tgt, cum);

    // ---- output 0: length regulate (after prep: cum ready)
    gather_kernel<<<(NB * MELMAX) / 4, 256, 0, stream>>>(x, cum, out);

    // ---- output 1: duration predictor (bf16 MFMA convs, R7-exact counted-vmcnt)
    conv_mfma_kernel<DM, DC, 128><<<NB * (LIN / 128) * (DC / 128), 256, 0, stream>>>(xb, wg1, b1, hbig);
    conv_mfma_kernel<DC, DM, 64><<<NB * (LIN / 128) * (DM / 64), 256, 0, stream>>>(hbig, wg2, b2, h2b);
    ln_kernel<<<NB * LIN / 4, 256, 0, stream>>>(h2b, g1, be1);
    conv_mfma_kernel<DM, DC, 128><<<NB * (LIN / 128) * (DC / 128), 256, 0, stream>>>(h2b, wg3, b3, hbig);
    conv_mfma_kernel<DC, DM, 64><<<NB * (LIN / 128) * (DM / 64), 256, 0, stream>>>(hbig, wg4, b4, xb);
    ln_linear_kernel<<<NB * LIN / 4, 256, 0, stream>>>(xb, g2, be2, wl, bl, dur);
}